// Round 3
// baseline (593.585 us; speedup 1.0000x reference)
//
#include <hip/hip_runtime.h>
#include <hip/hip_bf16.h>

// EnergyDecoder fused kernel for MI355X (gfx950) — Round 3 (R2 design, never
// benched due to broker timeout, + depth-2 prefetch).
// R1 lesson: barrier-coupled LDS pipeline with depth-0 prefetch exposed full
// memory latency on every K-step (172us, all pipes <10%). This version has NO
// LDS operands and NO K-loop barriers: per-wave register-direct MFMA GEMM with
// depth-2 rotating-register prefetch of the HBM stream (h) and L1/L2-hot W.

typedef _Float16 half8 __attribute__((ext_vector_type(8)));
typedef float    f32x4 __attribute__((ext_vector_type(4)));

#define NLIG 64
#define NTGT 512
#define KD   256     // 2*C

// ---------------------------------------------------------------------------
// Prep: wt[n][k] = fp16(W1[k][n]) for combined (WA1 | WB1) -> [256 n][256 k],
// so B-fragments are 8 contiguous k per lane. Also zero the 32-float output.
// ---------------------------------------------------------------------------
__global__ void ed_prep_kernel(const float* __restrict__ WA1,
                               const float* __restrict__ WB1,
                               _Float16* __restrict__ wt,
                               float* __restrict__ out) {
    int gid = blockIdx.x * 256 + threadIdx.x;   // 64 blocks x 256 thr = 16384
    int c   = gid >> 6;                          // k index 0..255
    int n0  = (gid & 63) * 4;                    // n quad
    const float* src = (n0 < 128) ? (WA1 + c * 128 + n0)
                                  : (WB1 + c * 128 + (n0 - 128));
    f32x4 v = *(const f32x4*)src;
#pragma unroll
    for (int j = 0; j < 4; ++j)
        wt[(size_t)(n0 + j) * KD + c] = (_Float16)v[j];
    if (gid < 32) out[gid] = 0.0f;
}

// ---------------------------------------------------------------------------
// Main kernel. Grid: 4096 blocks x 256 threads (4 waves, 2m x 2n).
// Block tile: 64 rows x 256 cols; wave tile: 32 rows x 128 cols.
// No LDS for operands, no barriers in the K-loop. 16x mfma 16x16x32 f16/step.
// A-stream: depth-2 prefetch through a 3-slot rotating register buffer (all
// indices compile-time after full unroll -> stays in VGPRs, rule #20 safe).
// ---------------------------------------------------------------------------
__global__ __launch_bounds__(256, 3) void ed_main_kernel(
    const float* __restrict__ lig_pos, const float* __restrict__ tgt_pos,
    const float* __restrict__ lig_vdw, const float* __restrict__ tgt_vdw,
    const float* __restrict__ lig_nm,  const float* __restrict__ tgt_nm,
    const float* __restrict__ ind,     const float* __restrict__ rotor,
    const float* __restrict__ h,       const _Float16* __restrict__ wt,
    const float* __restrict__ bA1, const float* __restrict__ WA2,
    const float* __restrict__ bA2,
    const float* __restrict__ bB1, const float* __restrict__ WB2,
    const float* __restrict__ bB2,
    const float* __restrict__ hbc, const float* __restrict__ hpc,
    const float* __restrict__ rtc,
    float* __restrict__ out)
{
    __shared__ float sRed[2][64];

    const int tid  = threadIdx.x;
    const int lane = tid & 63;
    const int wid  = tid >> 6;   // 0..3
    const int wm   = wid >> 1;   // 0..1 : 32-row half
    const int wn   = wid & 1;    // 0..1 : 128-col half (0=MLP A, 1=MLP B)
    const int lr   = lane & 15;
    const int lg   = lane >> 4;

    const int bx  = blockIdx.x;          // 0..4095
    const int b   = bx >> 9;             // 512 blocks per batch
    const int rem = bx & 511;
    const int l   = rem >> 3;
    const int t0  = (rem & 7) * 64;

    // per-lane A bases (rows of h), m-subtile 0/1; k-offsets fold to imm
    const float* aB0 = h + ((size_t)bx * 64 + wm * 32 + lr) * KD + lg * 8;
    const float* aB1 = aB0 + 16 * KD;
    // per-lane W base (cols of wt); n-subtile and k via static offsets
    const _Float16* wB = wt + ((size_t)(wn * 128 + lr)) * KD + lg * 8;

    f32x4 acc[2][8];
#pragma unroll
    for (int m = 0; m < 2; ++m)
#pragma unroll
        for (int n = 0; n < 8; ++n) acc[m][n] = 0;

    f32x4 al[3][2][2];   // [slot][m][half] — compile-time indices after unroll

    // prologue: load K-steps 0 and 1 (depth-2)
#pragma unroll
    for (int p = 0; p < 2; ++p) {
        al[p][0][0] = *(const f32x4*)(aB0 + p * 32);
        al[p][0][1] = *(const f32x4*)(aB0 + p * 32 + 4);
        al[p][1][0] = *(const f32x4*)(aB1 + p * 32);
        al[p][1][1] = *(const f32x4*)(aB1 + p * 32 + 4);
    }

#pragma unroll
    for (int ks = 0; ks < 8; ++ks) {
        const int cur = ks % 3;
        const int pre = (ks + 2) % 3;
        // depth-2 prefetch: issue loads for ks+2 before computing ks
        if (ks + 2 < 8) {
            al[pre][0][0] = *(const f32x4*)(aB0 + (ks + 2) * 32);
            al[pre][0][1] = *(const f32x4*)(aB0 + (ks + 2) * 32 + 4);
            al[pre][1][0] = *(const f32x4*)(aB1 + (ks + 2) * 32);
            al[pre][1][1] = *(const f32x4*)(aB1 + (ks + 2) * 32 + 4);
        }
        half8 ah[2];
#pragma unroll
        for (int m = 0; m < 2; ++m)
#pragma unroll
            for (int j = 0; j < 4; ++j) {
                ah[m][j]     = (_Float16)al[cur][m][0][j];
                ah[m][4 + j] = (_Float16)al[cur][m][1][j];
            }
#pragma unroll
        for (int n = 0; n < 8; ++n) {
            // W fragment: L1/L2-hot (same 16KB slice touched by all waves)
            half8 wh = *(const half8*)(wB + (size_t)n * 16 * KD + ks * 32);
            acc[0][n] = __builtin_amdgcn_mfma_f32_16x16x32_f16(
                ah[0], wh, acc[0][n], 0, 0, 0);
            acc[1][n] = __builtin_amdgcn_mfma_f32_16x16x32_f16(
                ah[1], wh, acc[1][n], 0, 0, 0);
        }
    }

    // ---- layer-2: relu + dot with W2, 16-lane column reduce ---------------
    float cb[8], cw[8];
#pragma unroll
    for (int n = 0; n < 8; ++n) {
        int c = n * 16 + lr;
        cb[n] = wn ? bB1[c] : bA1[c];
        cw[n] = wn ? WB2[c] : WA2[c];
    }
#pragma unroll
    for (int m = 0; m < 2; ++m)
#pragma unroll
        for (int r = 0; r < 4; ++r) {
            float p = 0.f;
#pragma unroll
            for (int n = 0; n < 8; ++n)
                p += fmaxf(acc[m][n][r] + cb[n], 0.f) * cw[n];
            p += __shfl_xor(p, 1);
            p += __shfl_xor(p, 2);
            p += __shfl_xor(p, 4);
            p += __shfl_xor(p, 8);
            if (lr == 0)
                sRed[wn][wm * 32 + m * 16 + lg * 4 + r] = p;
        }
    __syncthreads();

    // ---- per-row energy epilogue + block reduce (wave 0 only) -------------
    if (tid < 64) {
        const int t = t0 + tid;
        float mlpA = sRed[0][tid] + bA2[0];
        float mlpB = sRed[1][tid] + bB2[0];
        float Bp = tanhf(mlpB) * 0.2f;                      // DEV_VDW_RADIUS
        float lv = lig_vdw[b * NLIG + l];
        float tv = tgt_vdw[b * NTGT + t];
        float dx = lig_pos[(b * NLIG + l) * 3 + 0] - tgt_pos[(b * NTGT + t) * 3 + 0];
        float dy = lig_pos[(b * NLIG + l) * 3 + 1] - tgt_pos[(b * NTGT + t) * 3 + 1];
        float dz = lig_pos[(b * NLIG + l) * 3 + 2] - tgt_pos[(b * NTGT + t) * 3 + 2];
        float dm = sqrtf(dx * dx + dy * dy + dz * dz + 1e-10f);
        if (dm < 0.5f) dm = 1e10f;                          // DM_MIN mask
        float dm0  = lv + tv + Bp;
        float dm0c = (dm0 < 1e-4f) ? 1.0f : dm0;
        float qr = dm0c / dm;
        float q2 = qr * qr;
        float r6 = q2 * q2 * q2;
        float ve = fminf(r6 * r6 - 2.0f * r6, 100.0f);
        ve *= lig_nm[b * NLIG + l] * tgt_nm[b * NTGT + t];
        float Av = 1.0f / (1.0f + expf(-mlpA)) * (float)(0.0356 - 0.0178) + 0.0178f;
        float e0 = Av * ve;                                 // vdw
        float d = dm - dm0;
        const float* ib = ind + (size_t)b * 3 * NLIG * NTGT + (size_t)l * NTGT + t;
        float i0 = ib[0];
        float i1 = ib[NLIG * NTGT];
        float i2 = ib[2 * NLIG * NTGT];
        float e1 = fminf(fmaxf(d * i0 / -0.7f, 0.f), 1.f);  // hbond
        float e2 = fminf(fmaxf(d * i1 / -0.7f, 0.f), 1.f);  // metal
        float e3 = fminf(fmaxf((-d + 1.5f) * i2, 0.f), 1.f);// hydrophobic
#pragma unroll
        for (int off = 32; off > 0; off >>= 1) {
            e0 += __shfl_down(e0, off);
            e1 += __shfl_down(e1, off);
            e2 += __shfl_down(e2, off);
            e3 += __shfl_down(e3, off);
        }
        if (tid == 0) {
            float hc = hbc[0], pc = hpc[0], rc = rtc[0];
            float inv = 1.0f / (1.0f + rc * rc * rotor[b]);
            __hip_atomic_fetch_add(&out[b * 4 + 0], e0 * inv,
                                   __ATOMIC_RELAXED, __HIP_MEMORY_SCOPE_AGENT);
            __hip_atomic_fetch_add(&out[b * 4 + 1], -(hc * hc) * e1 * inv,
                                   __ATOMIC_RELAXED, __HIP_MEMORY_SCOPE_AGENT);
            __hip_atomic_fetch_add(&out[b * 4 + 2], -(hc * hc) * e2 * inv,
                                   __ATOMIC_RELAXED, __HIP_MEMORY_SCOPE_AGENT);
            __hip_atomic_fetch_add(&out[b * 4 + 3], -(pc * pc) * e3 * inv,
                                   __ATOMIC_RELAXED, __HIP_MEMORY_SCOPE_AGENT);
        }
    }
}

extern "C" void kernel_launch(void* const* d_in, const int* in_sizes, int n_in,
                              void* d_out, int out_size, void* d_ws, size_t ws_size,
                              hipStream_t stream) {
    (void)in_sizes; (void)n_in; (void)out_size; (void)ws_size;
    const float* lig_pos = (const float*)d_in[0];
    const float* tgt_pos = (const float*)d_in[1];
    const float* lig_vdw = (const float*)d_in[2];
    const float* tgt_vdw = (const float*)d_in[3];
    const float* lig_nm  = (const float*)d_in[4];
    const float* tgt_nm  = (const float*)d_in[5];
    const float* ind     = (const float*)d_in[6];
    const float* rotor   = (const float*)d_in[7];
    const float* h       = (const float*)d_in[8];
    const float* WA1     = (const float*)d_in[9];
    const float* bA1     = (const float*)d_in[10];
    const float* WA2     = (const float*)d_in[11];
    const float* bA2     = (const float*)d_in[12];
    const float* WB1     = (const float*)d_in[13];
    const float* bB1     = (const float*)d_in[14];
    const float* WB2     = (const float*)d_in[15];
    const float* bB2     = (const float*)d_in[16];
    const float* hbc     = (const float*)d_in[17];
    const float* hpc     = (const float*)d_in[18];
    const float* rtc     = (const float*)d_in[19];
    float* out   = (float*)d_out;
    _Float16* wt = (_Float16*)d_ws;   // 256*256 fp16 = 128 KiB scratch

    ed_prep_kernel<<<dim3(64), dim3(256), 0, stream>>>(WA1, WB1, wt, out);
    ed_main_kernel<<<dim3(4096), dim3(256), 0, stream>>>(
        lig_pos, tgt_pos, lig_vdw, tgt_vdw, lig_nm, tgt_nm, ind, rotor, h, wt,
        bA1, WA2, bA2, bB1, WB2, bB2, hbc, hpc, rtc, out);
}

// Round 4
// 474.835 us; speedup vs baseline: 1.2501x; 1.2501x over previous
//
#include <hip/hip_runtime.h>
#include <hip/hip_bf16.h>

// EnergyDecoder fused kernel for MI355X (gfx950) — Round 4.
// R1: per-K-step barriers + depth-0 prefetch -> 172us latency-bound.
// R3: register-direct, JIT W loads -> every MFMA waits an L2 round trip, 303us.
// R4 structure: W resident in registers (loaded once); h streamed via
// global_load_lds (async, no VGPR roundtrip), double-buffered 32-row tiles,
// ONE __syncthreads per tile (its implicit vmcnt(0) IS the "tile ready" wait);
// XOR-swizzled global source + swizzled ds_read (both-sides rule) for
// conflict-free b128 LDS reads; persistent blocks (2/CU) for a deep pipeline.

typedef _Float16 half8 __attribute__((ext_vector_type(8)));
typedef float    f32x4 __attribute__((ext_vector_type(4)));

#define NLIG 64
#define NTGT 512
#define KD   256     // 2*C
#define BM   32      // rows per tile
#define TPB  16      // tiles per block (512 blocks x 16 = 8192 tiles)

__device__ __forceinline__ void gload_lds16(const float* g, void* l) {
    __builtin_amdgcn_global_load_lds(
        (const __attribute__((address_space(1))) void*)g,
        (__attribute__((address_space(3))) void*)l, 16, 0, 0);
}

// ---------------------------------------------------------------------------
// Prep: wt[n][k] = fp16(W1[k][n]) for combined (WA1 | WB1) -> [256 n][256 k].
// Also zero the 32-float output (harness poisons d_out with 0xAA).
// ---------------------------------------------------------------------------
__global__ void ed_prep_kernel(const float* __restrict__ WA1,
                               const float* __restrict__ WB1,
                               _Float16* __restrict__ wt,
                               float* __restrict__ out) {
    int gid = blockIdx.x * 256 + threadIdx.x;   // 64 x 256 = 16384
    int c   = gid >> 6;                          // k 0..255
    int n0  = (gid & 63) * 4;                    // n quad
    const float* src = (n0 < 128) ? (WA1 + c * 128 + n0)
                                  : (WB1 + c * 128 + (n0 - 128));
    f32x4 v = *(const f32x4*)src;
#pragma unroll
    for (int j = 0; j < 4; ++j)
        wt[(size_t)(n0 + j) * KD + c] = (_Float16)v[j];
    if (gid < 32) out[gid] = 0.0f;
}

// ---------------------------------------------------------------------------
// Main kernel: 512 persistent blocks x 512 threads (8 waves).
// Wave w owns output cols [w*32, w*32+32): waves 0-3 = MLP A, 4-7 = MLP B.
// Per tile (32 rows): stage next tile async; 2 m-subtiles x 8 k-steps of
// mfma_f32_16x16x32_f16; layer-2 relu-dot partial per wave -> sRed; barrier;
// wave 0 does per-row energy + accumulates; final 4 atomics per block.
// ---------------------------------------------------------------------------
__global__ __launch_bounds__(512, 4) void ed_main_kernel(
    const float* __restrict__ lig_pos, const float* __restrict__ tgt_pos,
    const float* __restrict__ lig_vdw, const float* __restrict__ tgt_vdw,
    const float* __restrict__ lig_nm,  const float* __restrict__ tgt_nm,
    const float* __restrict__ ind,     const float* __restrict__ rotor,
    const float* __restrict__ h,       const _Float16* __restrict__ wt,
    const float* __restrict__ bA1, const float* __restrict__ WA2,
    const float* __restrict__ bA2,
    const float* __restrict__ bB1, const float* __restrict__ WB2,
    const float* __restrict__ bB2,
    const float* __restrict__ hbc, const float* __restrict__ hpc,
    const float* __restrict__ rtc,
    float* __restrict__ out)
{
    __shared__ float sA[2][BM][KD];      // 2 x 32KB, linear (global_load_lds dest)
    __shared__ float sRed[2][8][BM];     // 2KB, double-buffered partials

    const int tid  = threadIdx.x;
    const int lane = tid & 63;
    const int wid  = tid >> 6;    // 0..7
    const int lr   = lane & 15;
    const int lg   = lane >> 4;

    const int blk = blockIdx.x;   // 0..511
    const int b   = blk >> 6;     // 64 blocks per batch

    // ---- W resident in registers: cols [wid*32, wid*32+32), full K --------
    half8 wf[2][8];
#pragma unroll
    for (int n = 0; n < 2; ++n)
#pragma unroll
        for (int ks = 0; ks < 8; ++ks)
            wf[n][ks] = *(const half8*)(wt + (size_t)(wid * 32 + n * 16 + lr) * KD
                                           + ks * 32 + lg * 8);
    float cb[2], cw[2];
#pragma unroll
    for (int n = 0; n < 2; ++n) {
        int c = wid * 32 + n * 16 + lr;
        cb[n] = (c < 128) ? bA1[c] : bB1[c - 128];
        cw[n] = (c < 128) ? WA2[c] : WB2[c - 128];
    }

    float ea0 = 0.f, ea1 = 0.f, ea2 = 0.f, ea3 = 0.f;

    // staging: per wave 4 rows, one global_load_lds (64 lanes x 16B = 1 row)
    // LDS dest linear; global source pre-swizzled: lane j loads slot j^(r&7).
    auto stage = [&](int t, int bufi) {
        const size_t Rbase = ((size_t)blk * TPB + t) * BM;
#pragma unroll
        for (int i = 0; i < 4; ++i) {
            const int r = wid * 4 + i;
            const float* gp = h + (Rbase + r) * KD + ((lane ^ (r & 7)) << 2);
            gload_lds16(gp, (void*)&sA[bufi][r][0]);
        }
    };

    stage(0, 0);
    __syncthreads();   // implicit vmcnt(0): tile 0 landed

    for (int t = 0; t < TPB; ++t) {
        const int cur = t & 1;
        if (t + 1 < TPB) stage(t + 1, cur ^ 1);   // async, drains at barrier

        // ---- GEMM + layer-2 partial on buf[cur] ---------------------------
#pragma unroll
        for (int m = 0; m < 2; ++m) {
            f32x4 acc0 = {0, 0, 0, 0}, acc1 = {0, 0, 0, 0};
            const int r = m * 16 + lr;
            const int sw = r & 7;
#pragma unroll
            for (int ks = 0; ks < 8; ++ks) {
                const int s0 = ks * 8 + lg * 2;
                f32x4 a0 = *(const f32x4*)&sA[cur][r][(s0 ^ sw) << 2];
                f32x4 a1 = *(const f32x4*)&sA[cur][r][((s0 + 1) ^ sw) << 2];
                half8 ah;
#pragma unroll
                for (int j = 0; j < 4; ++j) {
                    ah[j]     = (_Float16)a0[j];
                    ah[4 + j] = (_Float16)a1[j];
                }
                acc0 = __builtin_amdgcn_mfma_f32_16x16x32_f16(ah, wf[0][ks], acc0, 0, 0, 0);
                acc1 = __builtin_amdgcn_mfma_f32_16x16x32_f16(ah, wf[1][ks], acc1, 0, 0, 0);
            }
            // layer-2: relu + dot(W2) over this wave's 32 cols, 16-lane reduce
#pragma unroll
            for (int q = 0; q < 4; ++q) {
                float p = fmaxf(acc0[q] + cb[0], 0.f) * cw[0]
                        + fmaxf(acc1[q] + cb[1], 0.f) * cw[1];
                p += __shfl_xor(p, 1);
                p += __shfl_xor(p, 2);
                p += __shfl_xor(p, 4);
                p += __shfl_xor(p, 8);
                if (lr == 0) sRed[cur][wid][m * 16 + lg * 4 + q] = p;
            }
        }
        __syncthreads();   // sRed visible + next tile's loads drained (vmcnt 0)

        // ---- per-row energy, wave 0 only (others proceed to next tile) ----
        if (wid == 0 && lane < BM) {
            const int Tb = blk * TPB + t - b * 1024;   // tile within batch
            const int l  = Tb >> 4;
            const int tt = ((Tb & 15) << 5) + lane;
            float mlpA = sRed[cur][0][lane] + sRed[cur][1][lane]
                       + sRed[cur][2][lane] + sRed[cur][3][lane] + bA2[0];
            float mlpB = sRed[cur][4][lane] + sRed[cur][5][lane]
                       + sRed[cur][6][lane] + sRed[cur][7][lane] + bB2[0];
            float Bp = tanhf(mlpB) * 0.2f;                  // DEV_VDW_RADIUS
            float lv = lig_vdw[b * NLIG + l];
            float tv = tgt_vdw[b * NTGT + tt];
            float dx = lig_pos[(b * NLIG + l) * 3 + 0] - tgt_pos[(b * NTGT + tt) * 3 + 0];
            float dy = lig_pos[(b * NLIG + l) * 3 + 1] - tgt_pos[(b * NTGT + tt) * 3 + 1];
            float dz = lig_pos[(b * NLIG + l) * 3 + 2] - tgt_pos[(b * NTGT + tt) * 3 + 2];
            float dm = sqrtf(dx * dx + dy * dy + dz * dz + 1e-10f);
            if (dm < 0.5f) dm = 1e10f;                      // DM_MIN mask
            float dm0  = lv + tv + Bp;
            float dm0c = (dm0 < 1e-4f) ? 1.0f : dm0;
            float qr = dm0c / dm;
            float q2 = qr * qr;
            float r6 = q2 * q2 * q2;
            float ve = fminf(r6 * r6 - 2.0f * r6, 100.0f);
            ve *= lig_nm[b * NLIG + l] * tgt_nm[b * NTGT + tt];
            float Av = 1.0f / (1.0f + expf(-mlpA)) * (float)(0.0356 - 0.0178) + 0.0178f;
            ea0 += Av * ve;                                 // vdw
            float d = dm - dm0;
            const float* ib = ind + (size_t)b * 3 * NLIG * NTGT
                                  + (size_t)l * NTGT + tt;
            float i0 = ib[0];
            float i1 = ib[NLIG * NTGT];
            float i2 = ib[2 * NLIG * NTGT];
            ea1 += fminf(fmaxf(d * i0 / -0.7f, 0.f), 1.f);  // hbond
            ea2 += fminf(fmaxf(d * i1 / -0.7f, 0.f), 1.f);  // metal
            ea3 += fminf(fmaxf((-d + 1.5f) * i2, 0.f), 1.f);// hydrophobic
        }
    }

    // ---- block-level reduce (wave 0, 32 active lanes) + atomics -----------
    if (wid == 0) {
#pragma unroll
        for (int off = 16; off > 0; off >>= 1) {
            ea0 += __shfl_xor(ea0, off);
            ea1 += __shfl_xor(ea1, off);
            ea2 += __shfl_xor(ea2, off);
            ea3 += __shfl_xor(ea3, off);
        }
        if (lane == 0) {
            float hc = hbc[0], pc = hpc[0], rc = rtc[0];
            float inv = 1.0f / (1.0f + rc * rc * rotor[b]);
            __hip_atomic_fetch_add(&out[b * 4 + 0], ea0 * inv,
                                   __ATOMIC_RELAXED, __HIP_MEMORY_SCOPE_AGENT);
            __hip_atomic_fetch_add(&out[b * 4 + 1], -(hc * hc) * ea1 * inv,
                                   __ATOMIC_RELAXED, __HIP_MEMORY_SCOPE_AGENT);
            __hip_atomic_fetch_add(&out[b * 4 + 2], -(hc * hc) * ea2 * inv,
                                   __ATOMIC_RELAXED, __HIP_MEMORY_SCOPE_AGENT);
            __hip_atomic_fetch_add(&out[b * 4 + 3], -(pc * pc) * ea3 * inv,
                                   __ATOMIC_RELAXED, __HIP_MEMORY_SCOPE_AGENT);
        }
    }
}

extern "C" void kernel_launch(void* const* d_in, const int* in_sizes, int n_in,
                              void* d_out, int out_size, void* d_ws, size_t ws_size,
                              hipStream_t stream) {
    (void)in_sizes; (void)n_in; (void)out_size; (void)ws_size;
    const float* lig_pos = (const float*)d_in[0];
    const float* tgt_pos = (const float*)d_in[1];
    const float* lig_vdw = (const float*)d_in[2];
    const float* tgt_vdw = (const float*)d_in[3];
    const float* lig_nm  = (const float*)d_in[4];
    const float* tgt_nm  = (const float*)d_in[5];
    const float* ind     = (const float*)d_in[6];
    const float* rotor   = (const float*)d_in[7];
    const float* h       = (const float*)d_in[8];
    const float* WA1     = (const float*)d_in[9];
    const float* bA1     = (const float*)d_in[10];
    const float* WA2     = (const float*)d_in[11];
    const float* bA2     = (const float*)d_in[12];
    const float* WB1     = (const float*)d_in[13];
    const float* bB1     = (const float*)d_in[14];
    const float* WB2     = (const float*)d_in[15];
    const float* bB2     = (const float*)d_in[16];
    const float* hbc     = (const float*)d_in[17];
    const float* hpc     = (const float*)d_in[18];
    const float* rtc     = (const float*)d_in[19];
    float* out   = (float*)d_out;
    _Float16* wt = (_Float16*)d_ws;   // 256*256 fp16 = 128 KiB scratch

    ed_prep_kernel<<<dim3(64), dim3(256), 0, stream>>>(WA1, WB1, wt, out);
    ed_main_kernel<<<dim3(512), dim3(512), 0, stream>>>(
        lig_pos, tgt_pos, lig_vdw, tgt_vdw, lig_nm, tgt_nm, ind, rotor, h, wt,
        bA1, WA2, bA2, bB1, WB2, bB2, hbc, hpc, rtc, out);
}